// Round 6
// baseline (1422.125 us; speedup 1.0000x reference)
//
#include <hip/hip_runtime.h>
#include <type_traits>

#define DEVINL __device__ __forceinline__

typedef __fp16 f16;
typedef __fp16 f16x2 __attribute__((ext_vector_type(2)));
typedef __fp16 f16x8 __attribute__((ext_vector_type(8)));

constexpr int Hh = 8;    // hidden size
constexpr int G3 = 24;   // 3*H gate rows
constexpr int TT = 512;  // timesteps

// Activation scales folded into weights/biases at register-load time:
//   sigmoid(v) = rcp(1 + exp2(-log2e * v))
//   tanh(v)    = (1 - e2) * rcp(1 + e2),  e2 = exp2(-2*log2e * v)
constexpr float SNEG  = -1.44269504088896340736f;  // -log2(e)
constexpr float SNEG2 = -2.88539008177792681472f;  // -2*log2(e)

DEVINL float dot2(f16x2 a, f16x2 b, float c) {
#if __has_builtin(__builtin_amdgcn_fdot2)
    return __builtin_amdgcn_fdot2(a, b, c, false);   // v_dot2_f32_f16
#else
    return fmaf((float)a[1], (float)b[1], fmaf((float)a[0], (float)b[0], c));
#endif
}

// Load one x row into f16x2 words. TWO_IN: row = concat(xf[0:8], xb[0:8]).
template <typename InT, bool TWO_IN>
DEVINL void load_x(f16x2* d, const InT* pf, const InT* pb) {
    if constexpr (std::is_same<InT, float>::value) {
        const float4* p4 = (const float4*)pf;          // 8 floats, one source
        float4 v0 = p4[0], v1 = p4[1];
        d[0] = __builtin_amdgcn_cvt_pkrtz(v0.x, v0.y);
        d[1] = __builtin_amdgcn_cvt_pkrtz(v0.z, v0.w);
        d[2] = __builtin_amdgcn_cvt_pkrtz(v1.x, v1.y);
        d[3] = __builtin_amdgcn_cvt_pkrtz(v1.z, v1.w);
    } else {
        f16x8 a = *(const f16x8*)pf;                   // 16B
        d[0] = __builtin_shufflevector(a, a, 0, 1);
        d[1] = __builtin_shufflevector(a, a, 2, 3);
        d[2] = __builtin_shufflevector(a, a, 4, 5);
        d[3] = __builtin_shufflevector(a, a, 6, 7);
        if constexpr (TWO_IN) {
            f16x8 b = *(const f16x8*)pb;               // 16B
            d[4] = __builtin_shufflevector(b, b, 0, 1);
            d[5] = __builtin_shufflevector(b, b, 2, 3);
            d[6] = __builtin_shufflevector(b, b, 4, 5);
            d[7] = __builtin_shufflevector(b, b, 6, 7);
        }
    }
}

// TWO independent (sequence, direction) units per 8-lane group. Both chains
// share the same direction -> weights/biases are register-SHARED; only x
// buffers, h state, and one offset register duplicate. When chain 0 stalls on
// its LDS h-roundtrip / exp2 chain, the wave issues chain 1 -> converts
// dependency-stall cycles (39% idle at R5) into issue cycles at zero added
// instructions. Lane i owns gate rows {i, 8+i, 16+i} of its group's units.
template <typename InT, bool TWO_IN, bool LAST>
__global__ __launch_bounds__(64, 2) void gru_scan(
    const InT* __restrict__ xf,          // (n, T, 8) fwd half (raw rows for L0)
    const InT* __restrict__ xb,          // (n, T, 8) bwd half (null for L0)
    const float* __restrict__ Wih,       // (2, 24, IN_DIM)
    const float* __restrict__ Whh,       // (2, 24, 8)
    const float* __restrict__ bih,       // (2, 24)
    const float* __restrict__ bhh,       // (2, 24)
    f16* __restrict__ outF,              // (n, T, 8) fwd outputs
    f16* __restrict__ outB,              // (n, T, 8) bwd outputs
    float* __restrict__ last,            // (n, 16) only when LAST
    int n)
{
    constexpr int IN_DIM = TWO_IN ? 16 : 8;
    constexpr int QW = IN_DIM / 2;       // f16x2 words per row
    constexpr int XD = TT * 8;           // chain-1 element offset delta

    const int tid   = threadIdx.x;
    const int lane8 = tid & 7;
    const int grp   = tid >> 3;          // 8 groups per 64-thread block
    const int unit0 = blockIdx.x * 16 + grp * 2;
    const int dir   = unit0 >= n ? 1 : 0;  // blocks dir-uniform (n % 16 == 0)
    const int seq0  = unit0 - dir * n;     // chain 1 = seq0 + 1

    const int g0 = lane8, g1 = 8 + lane8, g2 = 16 + lane8;

    // 8 groups x 2 chains x 8 f16. Writes: 2B stride-1 per chain (free).
    // Reads: ds_read_b128 broadcast per 8-lane group, conflict-free.
    // Intra-wave exchange -> wave_barrier suffices.
    __shared__ __align__(16) f16 hsh[128];
    const int hb0 = grp * 16;            // chain-0 row
    const int hb1 = grp * 16 + 8;        // chain-1 row

    // ---- shared weights into registers, activation scale pre-folded ----
    const float* Wd = Wih + (size_t)dir * G3 * IN_DIM;
    f16x2 wi0[QW], wi1[QW], wi2[QW];
#pragma unroll
    for (int q = 0; q < QW; ++q) {
        wi0[q] = __builtin_amdgcn_cvt_pkrtz(Wd[g0 * IN_DIM + 2 * q] * SNEG,
                                            Wd[g0 * IN_DIM + 2 * q + 1] * SNEG);
        wi1[q] = __builtin_amdgcn_cvt_pkrtz(Wd[g1 * IN_DIM + 2 * q] * SNEG,
                                            Wd[g1 * IN_DIM + 2 * q + 1] * SNEG);
        wi2[q] = __builtin_amdgcn_cvt_pkrtz(Wd[g2 * IN_DIM + 2 * q] * SNEG2,
                                            Wd[g2 * IN_DIM + 2 * q + 1] * SNEG2);
    }
    const float* Hd = Whh + (size_t)dir * G3 * Hh;
    f16x2 wh0[Hh / 2], wh1[Hh / 2], wh2[Hh / 2];
#pragma unroll
    for (int q = 0; q < Hh / 2; ++q) {
        wh0[q] = __builtin_amdgcn_cvt_pkrtz(Hd[g0 * Hh + 2 * q] * SNEG,
                                            Hd[g0 * Hh + 2 * q + 1] * SNEG);
        wh1[q] = __builtin_amdgcn_cvt_pkrtz(Hd[g1 * Hh + 2 * q] * SNEG,
                                            Hd[g1 * Hh + 2 * q + 1] * SNEG);
        wh2[q] = __builtin_amdgcn_cvt_pkrtz(Hd[g2 * Hh + 2 * q] * SNEG2,
                                            Hd[g2 * Hh + 2 * q + 1] * SNEG2);
    }
    const float br  = (bih[dir * G3 + g0] + bhh[dir * G3 + g0]) * SNEG;
    const float bz  = (bih[dir * G3 + g1] + bhh[dir * G3 + g1]) * SNEG;
    const float bxn = bih[dir * G3 + g2] * SNEG2;
    const float bhn = bhh[dir * G3 + g2] * SNEG2;

    f16x2 h20[Hh / 2], h21[Hh / 2];
#pragma unroll
    for (int q = 0; q < Hh / 2; ++q) {
        h20[q] = f16x2{(f16)0.f, (f16)0.f};
        h21[q] = f16x2{(f16)0.f, (f16)0.f};
    }
    float hown0 = 0.f, hown1 = 0.f;      // own h elements (fp32 chains)

    const int t0 = dir ? (TT - 1) : 0;
    const int xstep = dir ? -8 : 8;
    const int ostep = dir ? -8 : 8;
    int xoff = (seq0 * TT + t0) * 8;     // shared running offset, chain1 = +XD
    int ooff = (seq0 * TT + t0) * 8 + lane8;
    f16* oP = LAST ? nullptr : (dir ? outB : outF);

    // layer-3 backward: only out_b[:, T-1] is consumed = its FIRST step
    const int steps = (LAST && dir) ? 1 : TT;

    f16x2 xA0[QW], xA1[QW], xB0[QW], xB1[QW];
    load_x<InT, TWO_IN>(xA0, xf + xoff, xb + xoff);
    load_x<InT, TWO_IN>(xA1, xf + xoff + XD, xb + xoff + XD);
    xoff += xstep;
    if (steps > 1) {
        load_x<InT, TWO_IN>(xB0, xf + xoff, xb + xoff);
        load_x<InT, TWO_IN>(xB1, xf + xoff + XD, xb + xoff + XD);
        xoff += xstep;
    }

#define GRU_STEP(X0, X1, PF)                                                  \
    {                                                                         \
        float sr0 = br, sz0 = bz, xn0 = bxn;                                  \
        float sr1 = br, sz1 = bz, xn1 = bxn;                                  \
        _Pragma("unroll")                                                     \
        for (int q = 0; q < QW; ++q) {                                        \
            sr0 = dot2(wi0[q], X0[q], sr0);                                   \
            sz0 = dot2(wi1[q], X0[q], sz0);                                   \
            xn0 = dot2(wi2[q], X0[q], xn0);                                   \
            sr1 = dot2(wi0[q], X1[q], sr1);                                   \
            sz1 = dot2(wi1[q], X1[q], sz1);                                   \
            xn1 = dot2(wi2[q], X1[q], xn1);                                   \
        }                                                                     \
        if (PF) {                                                             \
            load_x<InT, TWO_IN>(X0, xf + xoff, xb + xoff);                    \
            load_x<InT, TWO_IN>(X1, xf + xoff + XD, xb + xoff + XD);          \
            xoff += xstep;                                                    \
        }                                                                     \
        float hn0 = bhn, hn1 = bhn;                                           \
        _Pragma("unroll")                                                     \
        for (int q = 0; q < Hh / 2; ++q) {                                    \
            sr0 = dot2(wh0[q], h20[q], sr0);                                  \
            sz0 = dot2(wh1[q], h20[q], sz0);                                  \
            hn0 = dot2(wh2[q], h20[q], hn0);                                  \
            sr1 = dot2(wh0[q], h21[q], sr1);                                  \
            sz1 = dot2(wh1[q], h21[q], sz1);                                  \
            hn1 = dot2(wh2[q], h21[q], hn1);                                  \
        }                                                                     \
        float r0 = __builtin_amdgcn_rcpf(1.f + __builtin_amdgcn_exp2f(sr0));  \
        float r1 = __builtin_amdgcn_rcpf(1.f + __builtin_amdgcn_exp2f(sr1));  \
        float z0 = __builtin_amdgcn_rcpf(1.f + __builtin_amdgcn_exp2f(sz0));  \
        float z1 = __builtin_amdgcn_rcpf(1.f + __builtin_amdgcn_exp2f(sz1));  \
        float v0 = fminf(fmaf(r0, hn0, xn0), 60.f);  /* NaN guard */          \
        float v1 = fminf(fmaf(r1, hn1, xn1), 60.f);                           \
        float e0 = __builtin_amdgcn_exp2f(v0);                                \
        float e1 = __builtin_amdgcn_exp2f(v1);                                \
        float nn0 = (1.f - e0) * __builtin_amdgcn_rcpf(1.f + e0);             \
        float nn1 = (1.f - e1) * __builtin_amdgcn_rcpf(1.f + e1);             \
        float hA = fmaf(z0, hown0 - nn0, nn0);     /* (1-z)*n + z*h */        \
        float hB = fmaf(z1, hown1 - nn1, nn1);                                \
        hown0 = hA; hown1 = hB;                                               \
        f16 hf0 = (f16)hA, hf1 = (f16)hB;                                     \
        if (!LAST) { oP[ooff] = hf0; oP[ooff + XD] = hf1; ooff += ostep; }    \
        hsh[hb0 + lane8] = hf0;                                               \
        hsh[hb1 + lane8] = hf1;                                               \
        __builtin_amdgcn_wave_barrier();                                      \
        f16x8 hv0 = *(const f16x8*)&hsh[hb0];                                 \
        f16x8 hv1 = *(const f16x8*)&hsh[hb1];                                 \
        h20[0] = __builtin_shufflevector(hv0, hv0, 0, 1);                     \
        h20[1] = __builtin_shufflevector(hv0, hv0, 2, 3);                     \
        h20[2] = __builtin_shufflevector(hv0, hv0, 4, 5);                     \
        h20[3] = __builtin_shufflevector(hv0, hv0, 6, 7);                     \
        h21[0] = __builtin_shufflevector(hv1, hv1, 0, 1);                     \
        h21[1] = __builtin_shufflevector(hv1, hv1, 2, 3);                     \
        h21[2] = __builtin_shufflevector(hv1, hv1, 4, 5);                     \
        h21[3] = __builtin_shufflevector(hv1, hv1, 6, 7);                     \
    }

    int s = 0;
    for (; s + 2 < steps; s += 2) {
        GRU_STEP(xA0, xA1, true);
        GRU_STEP(xB0, xB1, true);
    }
    GRU_STEP(xA0, xA1, false);
    if (steps > 1) GRU_STEP(xB0, xB1, false);
#undef GRU_STEP

    if (LAST) {
        last[(size_t)seq0 * 16 + dir * 8 + lane8] = hown0;
        last[(size_t)(seq0 + 1) * 16 + dir * 8 + lane8] = hown1;
    }
}

// last (n,16) fp32 -> lin1(16->8) -> LeakyReLU(0.2) -> lin2(8->8) -> fp32 out
__global__ void head_kernel(const float* __restrict__ last,
                            const float* __restrict__ w1, const float* __restrict__ b1,
                            const float* __restrict__ w2, const float* __restrict__ b2,
                            float* __restrict__ out, int n)
{
    int i = blockIdx.x * blockDim.x + threadIdx.x;
    if (i >= n) return;
    const float* v = last + (size_t)i * 16;
    float h1[8];
#pragma unroll
    for (int j = 0; j < 8; ++j) {
        float a = b1[j];
#pragma unroll
        for (int k = 0; k < 16; ++k) a = fmaf(w1[j * 16 + k], v[k], a);
        h1[j] = a >= 0.f ? a : 0.2f * a;
    }
#pragma unroll
    for (int j = 0; j < 8; ++j) {
        float o = b2[j];
#pragma unroll
        for (int k = 0; k < 8; ++k) o = fmaf(w2[j * 8 + k], h1[k], o);
        out[(size_t)i * 8 + j] = o;
    }
}

extern "C" void kernel_launch(void* const* d_in, const int* in_sizes, int n_in,
                              void* d_out, int out_size, void* d_ws, size_t ws_size,
                              hipStream_t stream)
{
    const float* raw  = (const float*)d_in[0];
    const float* Wih0 = (const float*)d_in[1];
    const float* Whh0 = (const float*)d_in[2];
    const float* bih0 = (const float*)d_in[3];
    const float* bhh0 = (const float*)d_in[4];
    const float* WihR = (const float*)d_in[5];
    const float* WhhR = (const float*)d_in[6];
    const float* bihR = (const float*)d_in[7];
    const float* bhhR = (const float*)d_in[8];
    const float* w1   = (const float*)d_in[9];
    const float* b1   = (const float*)d_in[10];
    const float* w2   = (const float*)d_in[11];
    const float* b2   = (const float*)d_in[12];

    const int n = in_sizes[0] / (TT * Hh);        // 12800 sequences
    const size_t hbE = (size_t)n * TT * 8;        // elems per (n,T,8) half-buffer
    dim3 blk(64);
    dim3 grid((unsigned)((2 * n) / 16));          // 16 units per 64-thread block
    dim3 hblk(256);
    dim3 hgrid((unsigned)((n + 255) / 256));

    // Per-direction f16 half-buffers: AF/AB and BF/BB (ping-pong), then lastb.
    f16* AF = (f16*)d_ws;
    f16* AB = AF + hbE;
    f16* BF = AB + hbE;
    f16* BB = BF + hbE;
    float* lastb = (float*)(BB + hbE);

    gru_scan<float, false, false><<<grid, blk, 0, stream>>>(
        raw, (const float*)nullptr, Wih0, Whh0, bih0, bhh0,
        AF, AB, (float*)nullptr, n);
    gru_scan<f16, true, false><<<grid, blk, 0, stream>>>(
        AF, AB, WihR + 0 * 2 * G3 * 16, WhhR + 0 * 2 * G3 * 8,
        bihR + 0 * 2 * G3, bhhR + 0 * 2 * G3, BF, BB, (float*)nullptr, n);
    gru_scan<f16, true, false><<<grid, blk, 0, stream>>>(
        BF, BB, WihR + 1 * 2 * G3 * 16, WhhR + 1 * 2 * G3 * 8,
        bihR + 1 * 2 * G3, bhhR + 1 * 2 * G3, AF, AB, (float*)nullptr, n);
    gru_scan<f16, true, true><<<grid, blk, 0, stream>>>(
        AF, AB, WihR + 2 * 2 * G3 * 16, WhhR + 2 * 2 * G3 * 8,
        bihR + 2 * 2 * G3, bhhR + 2 * 2 * G3,
        (f16*)nullptr, (f16*)nullptr, lastb, n);
    head_kernel<<<hgrid, hblk, 0, stream>>>(
        lastb, w1, b1, w2, b2, (float*)d_out, n);
}